// Round 7
// baseline (732.398 us; speedup 1.0000x reference)
//
#include <hip/hip_runtime.h>

// VQ nearest-codebook via split-bf16 MFMA GEMM + fp32 rescue.
// score(n,k) = 0.5*|e_k|^2 - z_n.e_k (monotone in squared distance)
//
// x = hi + lo (hi=bf16(x), lo=bf16(x-hi)); z.e ~ zhi.ehi + zlo.ehi + zhi.elo
// -> one bf16 GEMM, K=768, fp32 MFMA accum. Pass-1 emits top-2 per
// (token, 128-code slab); vq_pick rescores near-ties (tau=0.0625) in fp32.
//
// Round-7 change: 2-phase prefetch pipeline (T3 minimum form) in vq_gemm —
// issue next tile's global_load_lds BEFORE computing current tile, one
// __syncthreads per tile; double-buffered LDS (64 KB). XCD-chunked block
// swizzle (T1) so each XCD keeps its 8 B-slabs L2-resident.

typedef unsigned short ushort;
typedef __attribute__((ext_vector_type(8))) short short8;
typedef __attribute__((ext_vector_type(4))) float f32x4;

#define C 256
#define MTOK 16384
#define NCODE 8192
#define BM 128
#define BN 128
#define BK 64
#define NSLAB (NCODE / BN)   // 64
#define NTILE 12             // 3 segments x (C/BK)

__device__ __forceinline__ ushort bf16_rne(float x) {
    unsigned u = __float_as_uint(x);
    return (ushort)((u + 0x7FFFu + ((u >> 16) & 1u)) >> 16);
}

__device__ __forceinline__ bool lexlt(float as, int ai, float bs, int bi) {
    return as < bs || (as == bs && ai < bi);
}

// top2 (s1,i1,s2,i2) <- top2 of {self sorted pair, other sorted pair}
__device__ __forceinline__ void merge2(float& s1, int& i1, float& s2, int& i2,
                                       float os1, int oi1, float os2, int oi2) {
    if (lexlt(os1, oi1, s1, i1)) {
        float ns2; int ni2;
        if (lexlt(s1, i1, os2, oi2)) { ns2 = s1; ni2 = i1; }
        else                         { ns2 = os2; ni2 = oi2; }
        s2 = ns2; i2 = ni2; s1 = os1; i1 = oi1;
    } else if (lexlt(os1, oi1, s2, i2)) {
        s2 = os1; i2 = oi1;
    }
}

__device__ __forceinline__ void gload_lds16(const ushort* g, ushort* l) {
    __builtin_amdgcn_global_load_lds(
        (const __attribute__((address_space(1))) unsigned int*)g,
        (__attribute__((address_space(3))) unsigned int*)l, 16, 0, 0);
}

__global__ __launch_bounds__(64) void vq_norms(const float* __restrict__ emb,
                                               float* __restrict__ hn) {
    const int k = blockIdx.x;
    const int lane = threadIdx.x;
    const float4 v = *reinterpret_cast<const float4*>(emb + (size_t)k * C + lane * 4);
    float s = v.x * v.x + v.y * v.y + v.z * v.z + v.w * v.w;
    #pragma unroll
    for (int off = 32; off; off >>= 1) s += __shfl_down(s, off);
    if (lane == 0) hn[k] = 0.5f * s;
}

__global__ __launch_bounds__(256) void vq_split(const float* __restrict__ src,
                                                ushort* __restrict__ hi,
                                                ushort* __restrict__ lo, int n4) {
    typedef __attribute__((ext_vector_type(4))) ushort us4;
    const float4* s4 = reinterpret_cast<const float4*>(src);
    us4* h4 = reinterpret_cast<us4*>(hi);
    us4* l4 = reinterpret_cast<us4*>(lo);
    for (int i = blockIdx.x * 256 + threadIdx.x; i < n4; i += gridDim.x * 256) {
        const float4 v = s4[i];
        us4 h, l;
        float f[4] = {v.x, v.y, v.z, v.w};
        #pragma unroll
        for (int j = 0; j < 4; ++j) {
            const ushort hb = bf16_rne(f[j]);
            const float hf = __uint_as_float((unsigned)hb << 16);
            h[j] = hb;
            l[j] = bf16_rne(f[j] - hf);
        }
        h4[i] = h;
        l4[i] = l;
    }
}

__global__ __launch_bounds__(256) void vq_gemm(
    const ushort* __restrict__ zhi, const ushort* __restrict__ zlo,
    const ushort* __restrict__ ehi, const ushort* __restrict__ elo,
    const float* __restrict__ hn, float4* __restrict__ slab) {
    __shared__ ushort At[2][BM * BK];   // 2 x 16 KB
    __shared__ ushort Bt[2][BN * BK];   // 2 x 16 KB

    const int tid = threadIdx.x;
    const int lane = tid & 63;
    const int wid = __builtin_amdgcn_readfirstlane(tid >> 6);
    const int wr = wid >> 1, wc = wid & 1;

    // XCD-chunked swizzle: 8192 blocks, each XCD gets 1024 contiguous wg
    // (= 8 n-slabs x 128 m-blocks -> B-slabs stay L2-resident per XCD).
    const int bid = blockIdx.x;
    const int wg = (bid & 7) * (8192 >> 3) + (bid >> 3);
    const int mbase = (wg & 127) * BM;
    const int nb = wg >> 7;
    const int nbase = nb * BN;

    // staging geometry: call i covers 32 rows; wave covers 8 rows (1 KB)
    const int srow = wid * 8 + (lane >> 3);      // + i*32
    const int schunk = (lane & 7) ^ (lane >> 3); // pre-swizzled source chunk

    f32x4 acc[4][4];
    #pragma unroll
    for (int a = 0; a < 4; ++a)
        #pragma unroll
        for (int b = 0; b < 4; ++b) acc[a][b] = (f32x4){0.f, 0.f, 0.f, 0.f};

    // stage tile t into buffer buf (t: seg = t>>2, kk = t&3)
    auto stage = [&](int t, int buf) {
        const int seg = t >> 2;
        const int k0 = (t & 3) * BK;
        const ushort* As = (seg == 1) ? zlo : zhi;
        const ushort* Bs = (seg == 2) ? elo : ehi;
        #pragma unroll
        for (int i = 0; i < 4; ++i) {
            const int row = i * 32 + srow;
            gload_lds16(As + (size_t)(mbase + row) * C + k0 + schunk * 8,
                        &At[buf][(i * 32 + wid * 8) * BK]);
        }
        #pragma unroll
        for (int i = 0; i < 4; ++i) {
            const int row = i * 32 + srow;
            gload_lds16(Bs + (size_t)(nbase + row) * C + k0 + schunk * 8,
                        &Bt[buf][(i * 32 + wid * 8) * BK]);
        }
    };

    stage(0, 0);
    __syncthreads();   // drains vmcnt(0): tile 0 resident

    #pragma unroll 1
    for (int t = 0; t < NTILE; ++t) {
        const int cur = t & 1;
        if (t + 1 < NTILE) stage(t + 1, cur ^ 1);   // loads fly during compute

        #pragma unroll
        for (int h = 0; h < 2; ++h) {
            short8 a[4], b[4];
            #pragma unroll
            for (int f = 0; f < 4; ++f) {
                const int ar = wr * 64 + f * 16 + (lane & 15);
                const int ag = h * 4 + (lane >> 4);
                a[f] = *reinterpret_cast<const short8*>(
                    &At[cur][ar * BK + ((ag ^ (ar & 7)) * 8)]);
                const int br = wc * 64 + f * 16 + (lane & 15);
                b[f] = *reinterpret_cast<const short8*>(
                    &Bt[cur][br * BK + ((ag ^ (br & 7)) * 8)]);
            }
            #pragma unroll
            for (int fi = 0; fi < 4; ++fi)
                #pragma unroll
                for (int fj = 0; fj < 4; ++fj)
                    acc[fi][fj] = __builtin_amdgcn_mfma_f32_16x16x32_bf16(
                        a[fi], b[fj], acc[fi][fj], 0, 0, 0);
        }
        __syncthreads();   // reads of cur done + next tile's loads drained
    }

    // epilogue: per-token top-2 over this block's 128 codes
    const int ng0 = nbase + wc * 64 + (lane & 15);
    float hv[4];
    #pragma unroll
    for (int fj = 0; fj < 4; ++fj) hv[fj] = hn[ng0 + fj * 16];

    float* tl = reinterpret_cast<float*>(At);  // [128 m][2 wc][4 f] overlay

    #pragma unroll
    for (int fi = 0; fi < 4; ++fi) {
        #pragma unroll
        for (int r = 0; r < 4; ++r) {
            float s1 = 3.4e38f, s2 = 3.4e38f;
            int i1 = 0x7fffffff, i2 = 0x7fffffff;
            #pragma unroll
            for (int fj = 0; fj < 4; ++fj) {   // ascending code id
                const float sc = hv[fj] - acc[fi][fj][r];
                const int id = ng0 + fj * 16;
                if (lexlt(sc, id, s1, i1)) { s2 = s1; i2 = i1; s1 = sc; i1 = id; }
                else if (lexlt(sc, id, s2, i2)) { s2 = sc; i2 = id; }
            }
            #pragma unroll
            for (int off = 1; off <= 8; off <<= 1) {   // within 16-lane subgroup
                const float os1 = __shfl_xor(s1, off), os2 = __shfl_xor(s2, off);
                const int oi1 = __shfl_xor(i1, off), oi2 = __shfl_xor(i2, off);
                merge2(s1, i1, s2, i2, os1, oi1, os2, oi2);
            }
            if ((lane & 15) == 0) {
                const int m = wr * 64 + fi * 16 + (lane >> 4) * 4 + r;
                float* p = &tl[(m * 2 + wc) * 4];
                p[0] = s1; p[1] = __int_as_float(i1);
                p[2] = s2; p[3] = __int_as_float(i2);
            }
        }
    }
    __syncthreads();

    if (tid < BM) {
        const float* p0 = &tl[(tid * 2 + 0) * 4];
        const float* p1 = &tl[(tid * 2 + 1) * 4];
        float s1 = p0[0], s2 = p0[2];
        int i1 = __float_as_int(p0[1]), i2 = __float_as_int(p0[3]);
        merge2(s1, i1, s2, i2, p1[0], __float_as_int(p1[1]),
               p1[2], __float_as_int(p1[3]));
        const int token = mbase + tid;
        slab[(size_t)token * NSLAB + nb] =
            (float4){s1, __int_as_float(i1), s2, __int_as_float(i2)};
    }
}

__global__ __launch_bounds__(256) void vq_pick(
    const float* __restrict__ z, const float* __restrict__ emb,
    const float4* __restrict__ slab, float* __restrict__ out) {
    const int token = blockIdx.x * 4 + (threadIdx.x >> 6);
    const int lane = threadIdx.x & 63;

    const float4 c = slab[(size_t)token * NSLAB + lane];
    const float cs1 = c.x, cs2 = c.z;
    const int ci1 = __float_as_int(c.y), ci2 = __float_as_int(c.w);

    float bs = cs1;
    int bi = ci1;
    #pragma unroll
    for (int off = 32; off; off >>= 1) {
        const float os = __shfl_xor(bs, off);
        const int oi = __shfl_xor(bi, off);
        if (lexlt(os, oi, bs, bi)) { bs = os; bi = oi; }
    }

    const float tau = 0.0625f;
    const unsigned long long m1 = __ballot(cs1 <= bs + tau);
    const unsigned long long m2 = __ballot(cs2 <= bs + tau);
    int winner = bi;

    if (__popcll(m1) + __popcll(m2) > 1) {
        const float4 z4 = *reinterpret_cast<const float4*>(
            z + (size_t)token * C + lane * 4);
        float best = 3.4e38f;
        int besti = 0x7fffffff;
        #pragma unroll 1
        for (int pass = 0; pass < 2; ++pass) {
            unsigned long long mm = pass ? m2 : m1;
            while (mm) {
                const int l = __builtin_ctzll(mm);
                mm &= mm - 1;
                const int cidx = __shfl(pass ? ci2 : ci1, l);
                const float4 e4 = *reinterpret_cast<const float4*>(
                    emb + (size_t)cidx * C + lane * 4);
                float p = 0.5f * (e4.x * e4.x + e4.y * e4.y + e4.z * e4.z +
                                  e4.w * e4.w)
                        - (z4.x * e4.x + z4.y * e4.y + z4.z * e4.z + z4.w * e4.w);
                #pragma unroll
                for (int off = 32; off; off >>= 1) p += __shfl_xor(p, off);
                if (lexlt(p, cidx, best, besti)) { best = p; besti = cidx; }
            }
        }
        winner = besti;
    }

    const float4 v = *reinterpret_cast<const float4*>(
        emb + (size_t)winner * C + lane * 4);
    *reinterpret_cast<float4*>(out + (size_t)token * C + lane * 4) = v;
}

extern "C" void kernel_launch(void* const* d_in, const int* in_sizes, int n_in,
                              void* d_out, int out_size, void* d_ws, size_t ws_size,
                              hipStream_t stream) {
    const float* z = (const float*)d_in[0];
    const float* emb = (const float*)d_in[1];
    float* out = (float*)d_out;

    char* w = (char*)d_ws;
    float* hn = (float*)w;            w += (size_t)NCODE * 4;
    ushort* zhi = (ushort*)w;         w += (size_t)MTOK * C * 2;
    ushort* zlo = (ushort*)w;         w += (size_t)MTOK * C * 2;
    ushort* ehi = (ushort*)w;         w += (size_t)NCODE * C * 2;
    ushort* elo = (ushort*)w;         w += (size_t)NCODE * C * 2;
    float4* slab = (float4*)w;        // MTOK*NSLAB*16B = 16.8 MB

    vq_norms<<<NCODE, 64, 0, stream>>>(emb, hn);
    vq_split<<<1024, 256, 0, stream>>>(z, zhi, zlo, MTOK * C / 4);
    vq_split<<<512, 256, 0, stream>>>(emb, ehi, elo, NCODE * C / 4);

    vq_gemm<<<(MTOK / BM) * (NCODE / BN), 256, 0, stream>>>(
        zhi, zlo, ehi, elo, hn, slab);

    vq_pick<<<MTOK / 4, 256, 0, stream>>>(z, emb, slab, out);
}

// Round 8
// 658.856 us; speedup vs baseline: 1.1116x; 1.1116x over previous
//
#include <hip/hip_runtime.h>

// VQ nearest-codebook via split-bf16 MFMA GEMM + fp32 rescue.
// score(n,k) = 0.5*|e_k|^2 - z_n.e_k (monotone in squared distance)
//
// x = hi + lo (hi=bf16(x), lo=bf16(x-hi)); z.e ~ zhi.ehi + zlo.ehi + zhi.elo
// -> one bf16 GEMM, K=768, fp32 MFMA accum. Pass-1 emits top-2 per
// (token, 256-code slab); vq_pick rescores near-ties (tau=0.0625) in fp32.
//
// Round-8: 256x256 tile (8 waves, per-wave 128x64) to escape the 128^2
// LDS-pipe roof; 2-phase double-buffered prefetch (128 KB LDS, 1 block/CU,
// m230/m248-verified ~650-680 TF at K~1024); natural 2D x-fast dispatch
// (round-6-proven L3 locality — hand XCD swizzle regressed FETCH 4x).

typedef unsigned short ushort;
typedef __attribute__((ext_vector_type(8))) short short8;
typedef __attribute__((ext_vector_type(4))) float f32x4;

#define C 256
#define MTOK 16384
#define NCODE 8192
#define BM 256
#define BN 256
#define BK 64
#define TPB 512
#define NSLAB (NCODE / BN)   // 32
#define NTILE 12             // 3 segments x (C/BK)

__device__ __forceinline__ ushort bf16_rne(float x) {
    unsigned u = __float_as_uint(x);
    return (ushort)((u + 0x7FFFu + ((u >> 16) & 1u)) >> 16);
}

__device__ __forceinline__ bool lexlt(float as, int ai, float bs, int bi) {
    return as < bs || (as == bs && ai < bi);
}

// top2 (s1,i1,s2,i2) <- top2 of {self sorted pair, other sorted pair}
__device__ __forceinline__ void merge2(float& s1, int& i1, float& s2, int& i2,
                                       float os1, int oi1, float os2, int oi2) {
    if (lexlt(os1, oi1, s1, i1)) {
        float ns2; int ni2;
        if (lexlt(s1, i1, os2, oi2)) { ns2 = s1; ni2 = i1; }
        else                         { ns2 = os2; ni2 = oi2; }
        s2 = ns2; i2 = ni2; s1 = os1; i1 = oi1;
    } else if (lexlt(os1, oi1, s2, i2)) {
        s2 = os1; i2 = oi1;
    }
}

__device__ __forceinline__ void gload_lds16(const ushort* g, ushort* l) {
    __builtin_amdgcn_global_load_lds(
        (const __attribute__((address_space(1))) unsigned int*)g,
        (__attribute__((address_space(3))) unsigned int*)l, 16, 0, 0);
}

__global__ __launch_bounds__(64) void vq_norms(const float* __restrict__ emb,
                                               float* __restrict__ hn) {
    const int k = blockIdx.x;
    const int lane = threadIdx.x;
    const float4 v = *reinterpret_cast<const float4*>(emb + (size_t)k * C + lane * 4);
    float s = v.x * v.x + v.y * v.y + v.z * v.z + v.w * v.w;
    #pragma unroll
    for (int off = 32; off; off >>= 1) s += __shfl_down(s, off);
    if (lane == 0) hn[k] = 0.5f * s;
}

__global__ __launch_bounds__(256) void vq_split(const float* __restrict__ src,
                                                ushort* __restrict__ hi,
                                                ushort* __restrict__ lo, int n4) {
    typedef __attribute__((ext_vector_type(4))) ushort us4;
    const float4* s4 = reinterpret_cast<const float4*>(src);
    us4* h4 = reinterpret_cast<us4*>(hi);
    us4* l4 = reinterpret_cast<us4*>(lo);
    for (int i = blockIdx.x * 256 + threadIdx.x; i < n4; i += gridDim.x * 256) {
        const float4 v = s4[i];
        us4 h, l;
        float f[4] = {v.x, v.y, v.z, v.w};
        #pragma unroll
        for (int j = 0; j < 4; ++j) {
            const ushort hb = bf16_rne(f[j]);
            const float hf = __uint_as_float((unsigned)hb << 16);
            h[j] = hb;
            l[j] = bf16_rne(f[j] - hf);
        }
        h4[i] = h;
        l4[i] = l;
    }
}

__global__ __launch_bounds__(TPB, 2) void vq_gemm(
    const ushort* __restrict__ zhi, const ushort* __restrict__ zlo,
    const ushort* __restrict__ ehi, const ushort* __restrict__ elo,
    const float* __restrict__ hn, float4* __restrict__ slab) {
    __shared__ ushort At[2][BM * BK];   // 2 x 32 KB
    __shared__ ushort Bt[2][BN * BK];   // 2 x 32 KB

    const int tid = threadIdx.x;
    const int lane = tid & 63;
    const int wid = __builtin_amdgcn_readfirstlane(tid >> 6);
    const int wr = wid >> 2;          // 0..1  (M half)
    const int wc = wid & 3;           // 0..3  (N quarter)
    const int mbase = blockIdx.x * BM;
    const int nb = blockIdx.y;
    const int nbase = nb * BN;

    // staging: one issue covers 512 thr x 16B = 64 rows; wave covers 8 rows
    const int srow = wid * 8 + (lane >> 3);      // + i*64
    const int schunk = (lane & 7) ^ (lane >> 3); // pre-swizzled source chunk

    f32x4 acc[8][4];
    #pragma unroll
    for (int a = 0; a < 8; ++a)
        #pragma unroll
        for (int b = 0; b < 4; ++b) acc[a][b] = (f32x4){0.f, 0.f, 0.f, 0.f};

    // stage K-tile t into buffer buf (t: seg = t>>2, kk = t&3)
    auto stage = [&](int t, int buf) {
        const int seg = t >> 2;
        const int k0 = (t & 3) * BK;
        const ushort* As = (seg == 1) ? zlo : zhi;
        const ushort* Bs = (seg == 2) ? elo : ehi;
        #pragma unroll
        for (int i = 0; i < 4; ++i) {
            const int row = i * 64 + srow;
            gload_lds16(As + (size_t)(mbase + row) * C + k0 + schunk * 8,
                        &At[buf][(i * 64 + wid * 8) * BK]);
        }
        #pragma unroll
        for (int i = 0; i < 4; ++i) {
            const int row = i * 64 + srow;
            gload_lds16(Bs + (size_t)(nbase + row) * C + k0 + schunk * 8,
                        &Bt[buf][(i * 64 + wid * 8) * BK]);
        }
    };

    stage(0, 0);
    __syncthreads();   // tile 0 resident

    #pragma unroll 1
    for (int t = 0; t < NTILE; ++t) {
        const int cur = t & 1;
        if (t + 1 < NTILE) stage(t + 1, cur ^ 1);   // loads fly during compute

        #pragma unroll
        for (int h = 0; h < 2; ++h) {
            short8 a[8], b[4];
            #pragma unroll
            for (int f = 0; f < 8; ++f) {
                const int ar = wr * 128 + f * 16 + (lane & 15);
                const int ag = h * 4 + (lane >> 4);
                a[f] = *reinterpret_cast<const short8*>(
                    &At[cur][ar * BK + ((ag ^ (ar & 7)) * 8)]);
            }
            #pragma unroll
            for (int f = 0; f < 4; ++f) {
                const int br = wc * 64 + f * 16 + (lane & 15);
                const int ag = h * 4 + (lane >> 4);
                b[f] = *reinterpret_cast<const short8*>(
                    &Bt[cur][br * BK + ((ag ^ (br & 7)) * 8)]);
            }
            #pragma unroll
            for (int fi = 0; fi < 8; ++fi)
                #pragma unroll
                for (int fj = 0; fj < 4; ++fj)
                    acc[fi][fj] = __builtin_amdgcn_mfma_f32_16x16x32_bf16(
                        a[fi], b[fj], acc[fi][fj], 0, 0, 0);
        }
        __syncthreads();   // reads of cur done + next tile's loads drained
    }

    // epilogue: per-token top-2 over this block's 256 codes
    const int ng0 = nbase + wc * 64 + (lane & 15);
    float hv[4];
    #pragma unroll
    for (int fj = 0; fj < 4; ++fj) hv[fj] = hn[ng0 + fj * 16];

    float* tl = reinterpret_cast<float*>(At);  // [256 m][4 wc][4 f] = 16 KB

    #pragma unroll
    for (int fi = 0; fi < 8; ++fi) {
        #pragma unroll
        for (int r = 0; r < 4; ++r) {
            float s1 = 3.4e38f, s2 = 3.4e38f;
            int i1 = 0x7fffffff, i2 = 0x7fffffff;
            #pragma unroll
            for (int fj = 0; fj < 4; ++fj) {   // ascending code id
                const float sc = hv[fj] - acc[fi][fj][r];
                const int id = ng0 + fj * 16;
                if (lexlt(sc, id, s1, i1)) { s2 = s1; i2 = i1; s1 = sc; i1 = id; }
                else if (lexlt(sc, id, s2, i2)) { s2 = sc; i2 = id; }
            }
            #pragma unroll
            for (int off = 1; off <= 8; off <<= 1) {   // within 16-lane subgroup
                const float os1 = __shfl_xor(s1, off), os2 = __shfl_xor(s2, off);
                const int oi1 = __shfl_xor(i1, off), oi2 = __shfl_xor(i2, off);
                merge2(s1, i1, s2, i2, os1, oi1, os2, oi2);
            }
            if ((lane & 15) == 0) {
                const int m = wr * 128 + fi * 16 + (lane >> 4) * 4 + r;
                float* p = &tl[(m * 4 + wc) * 4];
                p[0] = s1; p[1] = __int_as_float(i1);
                p[2] = s2; p[3] = __int_as_float(i2);
            }
        }
    }
    __syncthreads();

    if (tid < BM) {
        float s1 = 3.4e38f, s2 = 3.4e38f;
        int i1 = 0x7fffffff, i2 = 0x7fffffff;
        #pragma unroll
        for (int w = 0; w < 4; ++w) {    // ascending wc = ascending codes
            const float* p = &tl[(tid * 4 + w) * 4];
            merge2(s1, i1, s2, i2, p[0], __float_as_int(p[1]),
                   p[2], __float_as_int(p[3]));
        }
        const int token = mbase + tid;
        slab[(size_t)token * NSLAB + nb] =
            (float4){s1, __int_as_float(i1), s2, __int_as_float(i2)};
    }
}

__global__ __launch_bounds__(256) void vq_pick(
    const float* __restrict__ z, const float* __restrict__ emb,
    const float4* __restrict__ slab, float* __restrict__ out) {
    const int token = blockIdx.x * 4 + (threadIdx.x >> 6);
    const int lane = threadIdx.x & 63;

    float4 c = (float4){3.4e38f, __int_as_float(0x7fffffff),
                        3.4e38f, __int_as_float(0x7fffffff)};
    if (lane < NSLAB) c = slab[(size_t)token * NSLAB + lane];
    const float cs1 = c.x, cs2 = c.z;
    const int ci1 = __float_as_int(c.y), ci2 = __float_as_int(c.w);

    float bs = cs1;
    int bi = ci1;
    #pragma unroll
    for (int off = 32; off; off >>= 1) {
        const float os = __shfl_xor(bs, off);
        const int oi = __shfl_xor(bi, off);
        if (lexlt(os, oi, bs, bi)) { bs = os; bi = oi; }
    }

    const float tau = 0.0625f;
    const unsigned long long m1 = __ballot(cs1 <= bs + tau);
    const unsigned long long m2 = __ballot(cs2 <= bs + tau);
    int winner = bi;

    if (__popcll(m1) + __popcll(m2) > 1) {
        const float4 z4 = *reinterpret_cast<const float4*>(
            z + (size_t)token * C + lane * 4);
        float best = 3.4e38f;
        int besti = 0x7fffffff;
        #pragma unroll 1
        for (int pass = 0; pass < 2; ++pass) {
            unsigned long long mm = pass ? m2 : m1;
            while (mm) {
                const int l = __builtin_ctzll(mm);
                mm &= mm - 1;
                const int cidx = __shfl(pass ? ci2 : ci1, l);
                const float4 e4 = *reinterpret_cast<const float4*>(
                    emb + (size_t)cidx * C + lane * 4);
                float p = 0.5f * (e4.x * e4.x + e4.y * e4.y + e4.z * e4.z +
                                  e4.w * e4.w)
                        - (z4.x * e4.x + z4.y * e4.y + z4.z * e4.z + z4.w * e4.w);
                #pragma unroll
                for (int off = 32; off; off >>= 1) p += __shfl_xor(p, off);
                if (lexlt(p, cidx, best, besti)) { best = p; besti = cidx; }
            }
        }
        winner = besti;
    }

    const float4 v = *reinterpret_cast<const float4*>(
        emb + (size_t)winner * C + lane * 4);
    *reinterpret_cast<float4*>(out + (size_t)token * C + lane * 4) = v;
}

extern "C" void kernel_launch(void* const* d_in, const int* in_sizes, int n_in,
                              void* d_out, int out_size, void* d_ws, size_t ws_size,
                              hipStream_t stream) {
    const float* z = (const float*)d_in[0];
    const float* emb = (const float*)d_in[1];
    float* out = (float*)d_out;

    char* w = (char*)d_ws;
    float* hn = (float*)w;            w += (size_t)NCODE * 4;
    ushort* zhi = (ushort*)w;         w += (size_t)MTOK * C * 2;
    ushort* zlo = (ushort*)w;         w += (size_t)MTOK * C * 2;
    ushort* ehi = (ushort*)w;         w += (size_t)NCODE * C * 2;
    ushort* elo = (ushort*)w;         w += (size_t)NCODE * C * 2;
    float4* slab = (float4*)w;        // MTOK*NSLAB*16B = 8.4 MB

    vq_norms<<<NCODE, 64, 0, stream>>>(emb, hn);
    vq_split<<<1024, 256, 0, stream>>>(z, zhi, zlo, MTOK * C / 4);
    vq_split<<<512, 256, 0, stream>>>(emb, ehi, elo, NCODE * C / 4);

    vq_gemm<<<dim3(MTOK / BM, NCODE / BN), TPB, 0, stream>>>(
        zhi, zlo, ehi, elo, hn, slab);

    vq_pick<<<MTOK / 4, 256, 0, stream>>>(z, emb, slab, out);
}

// Round 9
// 529.067 us; speedup vs baseline: 1.3843x; 1.2453x over previous
//
#include <hip/hip_runtime.h>

// VQ nearest-codebook via bf16 MFMA GEMM + exact-fp32 rescue.
// score(n,k) = 0.5*|e_k|^2 - z_n.e_k (monotone in squared distance)
//
// Round-9: single bf16 rounding (no hi/lo split) -> K=256 GEMM (68.7 GFLOP,
// 3x less than r6-r8). Rounding error sigma~0.006, max~0.035; top-2 per
// 128-code slab + tau=0.25 exact-fp32 rescue guarantees exact argmin.
// GEMM structure = round-6 verbatim (128^2 tile, 32 KB LDS, ~3 blocks/CU,
// natural x-fast 2D grid) — the best-measured structure across r6/r7/r8.

typedef unsigned short ushort;
typedef __attribute__((ext_vector_type(8))) short short8;
typedef __attribute__((ext_vector_type(4))) float f32x4;

#define C 256
#define MTOK 16384
#define NCODE 8192
#define BM 128
#define BN 128
#define BK 64
#define NSLAB (NCODE / BN)   // 64
#define NTILE (C / BK)       // 4

__device__ __forceinline__ ushort bf16_rne(float x) {
    unsigned u = __float_as_uint(x);
    return (ushort)((u + 0x7FFFu + ((u >> 16) & 1u)) >> 16);
}

__device__ __forceinline__ bool lexlt(float as, int ai, float bs, int bi) {
    return as < bs || (as == bs && ai < bi);
}

// top2 (s1,i1,s2,i2) <- top2 of {self sorted pair, other sorted pair}
__device__ __forceinline__ void merge2(float& s1, int& i1, float& s2, int& i2,
                                       float os1, int oi1, float os2, int oi2) {
    if (lexlt(os1, oi1, s1, i1)) {
        float ns2; int ni2;
        if (lexlt(s1, i1, os2, oi2)) { ns2 = s1; ni2 = i1; }
        else                         { ns2 = os2; ni2 = oi2; }
        s2 = ns2; i2 = ni2; s1 = os1; i1 = oi1;
    } else if (lexlt(os1, oi1, s2, i2)) {
        s2 = os1; i2 = oi1;
    }
}

__device__ __forceinline__ void gload_lds16(const ushort* g, ushort* l) {
    __builtin_amdgcn_global_load_lds(
        (const __attribute__((address_space(1))) unsigned int*)g,
        (__attribute__((address_space(3))) unsigned int*)l, 16, 0, 0);
}

__global__ __launch_bounds__(64) void vq_norms(const float* __restrict__ emb,
                                               float* __restrict__ hn) {
    const int k = blockIdx.x;
    const int lane = threadIdx.x;
    const float4 v = *reinterpret_cast<const float4*>(emb + (size_t)k * C + lane * 4);
    float s = v.x * v.x + v.y * v.y + v.z * v.z + v.w * v.w;
    #pragma unroll
    for (int off = 32; off; off >>= 1) s += __shfl_down(s, off);
    if (lane == 0) hn[k] = 0.5f * s;
}

__global__ __launch_bounds__(256) void vq_cast(const float* __restrict__ src,
                                               ushort* __restrict__ dst, int n4) {
    typedef __attribute__((ext_vector_type(4))) ushort us4;
    const float4* s4 = reinterpret_cast<const float4*>(src);
    us4* d4 = reinterpret_cast<us4*>(dst);
    for (int i = blockIdx.x * 256 + threadIdx.x; i < n4; i += gridDim.x * 256) {
        const float4 v = s4[i];
        us4 h;
        h[0] = bf16_rne(v.x);
        h[1] = bf16_rne(v.y);
        h[2] = bf16_rne(v.z);
        h[3] = bf16_rne(v.w);
        d4[i] = h;
    }
}

__global__ __launch_bounds__(256) void vq_gemm(
    const ushort* __restrict__ zb, const ushort* __restrict__ eb,
    const float* __restrict__ hn, float4* __restrict__ slab) {
    __shared__ ushort At[BM * BK];   // 16 KB, swizzled addressing
    __shared__ ushort Bt[BN * BK];   // 16 KB

    const int tid = threadIdx.x;
    const int lane = tid & 63;
    const int wid = __builtin_amdgcn_readfirstlane(tid >> 6);
    const int wr = wid >> 1, wc = wid & 1;
    const int mbase = blockIdx.x * BM;
    const int nb = blockIdx.y;
    const int nbase = nb * BN;

    // staging geometry: call i covers 32 rows; wave covers 8 rows (1 KB)
    const int srow = wid * 8 + (lane >> 3);      // + i*32
    const int schunk = (lane & 7) ^ (lane >> 3); // pre-swizzled source chunk

    f32x4 acc[4][4];
    #pragma unroll
    for (int a = 0; a < 4; ++a)
        #pragma unroll
        for (int b = 0; b < 4; ++b) acc[a][b] = (f32x4){0.f, 0.f, 0.f, 0.f};

    #pragma unroll 1
    for (int kk = 0; kk < NTILE; ++kk) {
        const int k0 = kk * BK;
        __syncthreads();   // previous iteration's reads done
        #pragma unroll
        for (int i = 0; i < 4; ++i) {
            const int row = i * 32 + srow;
            gload_lds16(zb + (size_t)(mbase + row) * C + k0 + schunk * 8,
                        &At[(i * 32 + wid * 8) * BK]);
        }
        #pragma unroll
        for (int i = 0; i < 4; ++i) {
            const int row = i * 32 + srow;
            gload_lds16(eb + (size_t)(nbase + row) * C + k0 + schunk * 8,
                        &Bt[(i * 32 + wid * 8) * BK]);
        }
        __syncthreads();   // drains vmcnt (compiler) + barrier

        #pragma unroll
        for (int h = 0; h < 2; ++h) {
            short8 a[4], b[4];
            #pragma unroll
            for (int f = 0; f < 4; ++f) {
                const int ar = wr * 64 + f * 16 + (lane & 15);
                const int ag = h * 4 + (lane >> 4);
                a[f] = *reinterpret_cast<const short8*>(
                    &At[ar * BK + ((ag ^ (ar & 7)) * 8)]);
                const int br = wc * 64 + f * 16 + (lane & 15);
                b[f] = *reinterpret_cast<const short8*>(
                    &Bt[br * BK + ((ag ^ (br & 7)) * 8)]);
            }
            #pragma unroll
            for (int fi = 0; fi < 4; ++fi)
                #pragma unroll
                for (int fj = 0; fj < 4; ++fj)
                    acc[fi][fj] = __builtin_amdgcn_mfma_f32_16x16x32_bf16(
                        a[fi], b[fj], acc[fi][fj], 0, 0, 0);
        }
    }

    // epilogue: per-token top-2 over this block's 128 codes
    const int ng0 = nbase + wc * 64 + (lane & 15);
    float hv[4];
    #pragma unroll
    for (int fj = 0; fj < 4; ++fj) hv[fj] = hn[ng0 + fj * 16];

    __syncthreads();                         // all LDS reads done
    float* tl = reinterpret_cast<float*>(At);  // [128 m][2 wc][4 f] overlay

    #pragma unroll
    for (int fi = 0; fi < 4; ++fi) {
        #pragma unroll
        for (int r = 0; r < 4; ++r) {
            float s1 = 3.4e38f, s2 = 3.4e38f;
            int i1 = 0x7fffffff, i2 = 0x7fffffff;
            #pragma unroll
            for (int fj = 0; fj < 4; ++fj) {   // ascending code id
                const float sc = hv[fj] - acc[fi][fj][r];
                const int id = ng0 + fj * 16;
                if (lexlt(sc, id, s1, i1)) { s2 = s1; i2 = i1; s1 = sc; i1 = id; }
                else if (lexlt(sc, id, s2, i2)) { s2 = sc; i2 = id; }
            }
            #pragma unroll
            for (int off = 1; off <= 8; off <<= 1) {   // within 16-lane subgroup
                const float os1 = __shfl_xor(s1, off), os2 = __shfl_xor(s2, off);
                const int oi1 = __shfl_xor(i1, off), oi2 = __shfl_xor(i2, off);
                merge2(s1, i1, s2, i2, os1, oi1, os2, oi2);
            }
            if ((lane & 15) == 0) {
                const int m = wr * 64 + fi * 16 + (lane >> 4) * 4 + r;
                float* p = &tl[(m * 2 + wc) * 4];
                p[0] = s1; p[1] = __int_as_float(i1);
                p[2] = s2; p[3] = __int_as_float(i2);
            }
        }
    }
    __syncthreads();

    if (tid < BM) {
        const float* p0 = &tl[(tid * 2 + 0) * 4];
        const float* p1 = &tl[(tid * 2 + 1) * 4];
        float s1 = p0[0], s2 = p0[2];
        int i1 = __float_as_int(p0[1]), i2 = __float_as_int(p0[3]);
        merge2(s1, i1, s2, i2, p1[0], __float_as_int(p1[1]),
               p1[2], __float_as_int(p1[3]));
        const int token = mbase + tid;
        slab[(size_t)token * NSLAB + nb] =
            (float4){s1, __int_as_float(i1), s2, __int_as_float(i2)};
    }
}

__global__ __launch_bounds__(256) void vq_pick(
    const float* __restrict__ z, const float* __restrict__ emb,
    const float4* __restrict__ slab, float* __restrict__ out) {
    const int token = blockIdx.x * 4 + (threadIdx.x >> 6);
    const int lane = threadIdx.x & 63;

    const float4 c = slab[(size_t)token * NSLAB + lane];
    const float cs1 = c.x, cs2 = c.z;
    const int ci1 = __float_as_int(c.y), ci2 = __float_as_int(c.w);

    float bs = cs1;
    int bi = ci1;
    #pragma unroll
    for (int off = 32; off; off >>= 1) {
        const float os = __shfl_xor(bs, off);
        const int oi = __shfl_xor(bi, off);
        if (lexlt(os, oi, bs, bi)) { bs = os; bi = oi; }
    }

    const float tau = 0.25f;   // >> 2*max bf16-rounding score error (~0.07)
    const unsigned long long m1 = __ballot(cs1 <= bs + tau);
    const unsigned long long m2 = __ballot(cs2 <= bs + tau);
    int winner = bi;

    if (__popcll(m1) + __popcll(m2) > 1) {
        const float4 z4 = *reinterpret_cast<const float4*>(
            z + (size_t)token * C + lane * 4);
        float best = 3.4e38f;
        int besti = 0x7fffffff;
        #pragma unroll 1
        for (int pass = 0; pass < 2; ++pass) {
            unsigned long long mm = pass ? m2 : m1;
            while (mm) {
                const int l = __builtin_ctzll(mm);
                mm &= mm - 1;
                const int cidx = __shfl(pass ? ci2 : ci1, l);
                const float4 e4 = *reinterpret_cast<const float4*>(
                    emb + (size_t)cidx * C + lane * 4);
                float p = 0.5f * (e4.x * e4.x + e4.y * e4.y + e4.z * e4.z +
                                  e4.w * e4.w)
                        - (z4.x * e4.x + z4.y * e4.y + z4.z * e4.z + z4.w * e4.w);
                #pragma unroll
                for (int off = 32; off; off >>= 1) p += __shfl_xor(p, off);
                if (lexlt(p, cidx, best, besti)) { best = p; besti = cidx; }
            }
        }
        winner = besti;
    }

    const float4 v = *reinterpret_cast<const float4*>(
        emb + (size_t)winner * C + lane * 4);
    *reinterpret_cast<float4*>(out + (size_t)token * C + lane * 4) = v;
}

extern "C" void kernel_launch(void* const* d_in, const int* in_sizes, int n_in,
                              void* d_out, int out_size, void* d_ws, size_t ws_size,
                              hipStream_t stream) {
    const float* z = (const float*)d_in[0];
    const float* emb = (const float*)d_in[1];
    float* out = (float*)d_out;

    char* w = (char*)d_ws;
    float* hn = (float*)w;            w += (size_t)NCODE * 4;
    ushort* zb = (ushort*)w;          w += (size_t)MTOK * C * 2;
    ushort* eb = (ushort*)w;          w += (size_t)NCODE * C * 2;
    float4* slab = (float4*)w;        // MTOK*NSLAB*16B = 16.8 MB

    vq_norms<<<NCODE, 64, 0, stream>>>(emb, hn);
    vq_cast<<<1024, 256, 0, stream>>>(z, zb, MTOK * C / 4);
    vq_cast<<<512, 256, 0, stream>>>(emb, eb, NCODE * C / 4);

    vq_gemm<<<dim3(MTOK / BM, NCODE / BN), 256, 0, stream>>>(zb, eb, hn, slab);

    vq_pick<<<MTOK / 4, 256, 0, stream>>>(z, emb, slab, out);
}

// Round 10
// 340.476 us; speedup vs baseline: 2.1511x; 1.5539x over previous
//
#include <hip/hip_runtime.h>

// VQ nearest-codebook via bf16 MFMA GEMM + exact-fp32 rescue.
// score(n,k) = 0.5*|e_k|^2 - z_n.e_k (monotone in squared distance)
//
// Round-10: attack per-block fixed cost (r9 evidence: 520 us K-independent).
//  - BM=256 x BN=128, 8 waves, 4096 blocks (half of r9), 48 KB LDS, 3 blk/CU
//  - cheap epilogue: fj-fold -> 2 xor-merge steps -> padded LDS table
//    (144 B/token) -> per-thread serial merge of 8 entries. No 4-deep
//    swizzle chains.
// Main-loop staging/swizzle/MFMA mapping identical to r6/r9 (proven).

typedef unsigned short ushort;
typedef __attribute__((ext_vector_type(8))) short short8;
typedef __attribute__((ext_vector_type(4))) float f32x4;

#define C 256
#define MTOK 16384
#define NCODE 8192
#define BM 256
#define BN 128
#define BK 64
#define TPB 512
#define NSLAB (NCODE / BN)   // 64
#define NTILE (C / BK)       // 4
#define TROW 36              // floats per token row in epilogue table (144 B)

__device__ __forceinline__ ushort bf16_rne(float x) {
    unsigned u = __float_as_uint(x);
    return (ushort)((u + 0x7FFFu + ((u >> 16) & 1u)) >> 16);
}

__device__ __forceinline__ bool lexlt(float as, int ai, float bs, int bi) {
    return as < bs || (as == bs && ai < bi);
}

// top2 (s1,i1,s2,i2) <- top2 of {self sorted pair, other sorted pair}
__device__ __forceinline__ void merge2(float& s1, int& i1, float& s2, int& i2,
                                       float os1, int oi1, float os2, int oi2) {
    if (lexlt(os1, oi1, s1, i1)) {
        float ns2; int ni2;
        if (lexlt(s1, i1, os2, oi2)) { ns2 = s1; ni2 = i1; }
        else                         { ns2 = os2; ni2 = oi2; }
        s2 = ns2; i2 = ni2; s1 = os1; i1 = oi1;
    } else if (lexlt(os1, oi1, s2, i2)) {
        s2 = os1; i2 = oi1;
    }
}

__device__ __forceinline__ void gload_lds16(const ushort* g, ushort* l) {
    __builtin_amdgcn_global_load_lds(
        (const __attribute__((address_space(1))) unsigned int*)g,
        (__attribute__((address_space(3))) unsigned int*)l, 16, 0, 0);
}

__global__ __launch_bounds__(64) void vq_norms(const float* __restrict__ emb,
                                               float* __restrict__ hn) {
    const int k = blockIdx.x;
    const int lane = threadIdx.x;
    const float4 v = *reinterpret_cast<const float4*>(emb + (size_t)k * C + lane * 4);
    float s = v.x * v.x + v.y * v.y + v.z * v.z + v.w * v.w;
    #pragma unroll
    for (int off = 32; off; off >>= 1) s += __shfl_down(s, off);
    if (lane == 0) hn[k] = 0.5f * s;
}

__global__ __launch_bounds__(256) void vq_cast(const float* __restrict__ src,
                                               ushort* __restrict__ dst, int n4) {
    typedef __attribute__((ext_vector_type(4))) ushort us4;
    const float4* s4 = reinterpret_cast<const float4*>(src);
    us4* d4 = reinterpret_cast<us4*>(dst);
    for (int i = blockIdx.x * 256 + threadIdx.x; i < n4; i += gridDim.x * 256) {
        const float4 v = s4[i];
        us4 h;
        h[0] = bf16_rne(v.x);
        h[1] = bf16_rne(v.y);
        h[2] = bf16_rne(v.z);
        h[3] = bf16_rne(v.w);
        d4[i] = h;
    }
}

__global__ __launch_bounds__(TPB) void vq_gemm(
    const ushort* __restrict__ zb, const ushort* __restrict__ eb,
    const float* __restrict__ hn, float4* __restrict__ slab) {
    __shared__ ushort smem[(BM + BN) * BK];   // 48 KB staging
    ushort* At = smem;                         // [256 rows][64 c]
    ushort* Bt = smem + BM * BK;               // [128 rows][64 c]

    const int tid = threadIdx.x;
    const int lane = tid & 63;
    const int wid = __builtin_amdgcn_readfirstlane(tid >> 6);
    const int wr = wid >> 1;          // 0..3 (M quarter)
    const int wc = wid & 1;           // 0..1 (N half)
    const int mbase = blockIdx.x * BM;
    const int nb = blockIdx.y;
    const int nbase = nb * BN;

    // staging: one issue = 512 thr x 16 B = 64 rows; wave covers 8 rows
    const int srow = wid * 8 + (lane >> 3);      // + i*64
    const int schunk = (lane & 7) ^ (lane >> 3); // pre-swizzled source chunk

    f32x4 acc[4][4];
    #pragma unroll
    for (int a = 0; a < 4; ++a)
        #pragma unroll
        for (int b = 0; b < 4; ++b) acc[a][b] = (f32x4){0.f, 0.f, 0.f, 0.f};

    #pragma unroll 1
    for (int kk = 0; kk < NTILE; ++kk) {
        const int k0 = kk * BK;
        __syncthreads();   // previous iteration's reads done
        #pragma unroll
        for (int i = 0; i < 4; ++i) {
            const int row = i * 64 + srow;
            gload_lds16(zb + (size_t)(mbase + row) * C + k0 + schunk * 8,
                        &At[(i * 64 + wid * 8) * BK]);
        }
        #pragma unroll
        for (int i = 0; i < 2; ++i) {
            const int row = i * 64 + srow;
            gload_lds16(eb + (size_t)(nbase + row) * C + k0 + schunk * 8,
                        &Bt[(i * 64 + wid * 8) * BK]);
        }
        __syncthreads();   // drains vmcnt (compiler) + barrier

        #pragma unroll
        for (int h = 0; h < 2; ++h) {
            short8 a[4], b[4];
            #pragma unroll
            for (int f = 0; f < 4; ++f) {
                const int ar = wr * 64 + f * 16 + (lane & 15);
                const int ag = h * 4 + (lane >> 4);
                a[f] = *reinterpret_cast<const short8*>(
                    &At[ar * BK + ((ag ^ (ar & 7)) * 8)]);
                const int br = wc * 64 + f * 16 + (lane & 15);
                b[f] = *reinterpret_cast<const short8*>(
                    &Bt[br * BK + ((ag ^ (br & 7)) * 8)]);
            }
            #pragma unroll
            for (int fi = 0; fi < 4; ++fi)
                #pragma unroll
                for (int fj = 0; fj < 4; ++fj)
                    acc[fi][fj] = __builtin_amdgcn_mfma_f32_16x16x32_bf16(
                        a[fi], b[fj], acc[fi][fj], 0, 0, 0);
        }
    }

    // ---- epilogue: per-token top-2 over this block's 128 codes ----
    const int ng0 = nbase + wc * 64 + (lane & 15);
    float hv[4];
    #pragma unroll
    for (int fj = 0; fj < 4; ++fj) hv[fj] = hn[ng0 + fj * 16];

    __syncthreads();                          // all LDS reads done
    float* tl = reinterpret_cast<float*>(smem);  // [256 t][TROW floats] = 36 KB

    const int rg = lane >> 4;          // 0..3 (token sub-row)
    const int g  = (lane & 15) >> 2;   // 0..3 (4-lane code group)

    #pragma unroll
    for (int fi = 0; fi < 4; ++fi) {
        #pragma unroll
        for (int r = 0; r < 4; ++r) {
            float s1 = 3.4e38f, s2 = 3.4e38f;
            int i1 = 0x7fffffff, i2 = 0x7fffffff;
            #pragma unroll
            for (int fj = 0; fj < 4; ++fj) {
                const float sc = hv[fj] - acc[fi][fj][r];
                const int id = ng0 + fj * 16;
                if (lexlt(sc, id, s1, i1)) { s2 = s1; i2 = i1; s1 = sc; i1 = id; }
                else if (lexlt(sc, id, s2, i2)) { s2 = sc; i2 = id; }
            }
            // 2 xor-merge steps: fold 4-lane code group
            #pragma unroll
            for (int off = 1; off <= 2; off <<= 1) {
                const float os1 = __shfl_xor(s1, off), os2 = __shfl_xor(s2, off);
                const int oi1 = __shfl_xor(i1, off), oi2 = __shfl_xor(i2, off);
                merge2(s1, i1, s2, i2, os1, oi1, os2, oi2);
            }
            if ((lane & 3) == 0) {
                const int token = wr * 64 + fi * 16 + rg * 4 + r;
                float* p = &tl[token * TROW + (wc * 4 + g) * 4];
                p[0] = s1; p[1] = __int_as_float(i1);
                p[2] = s2; p[3] = __int_as_float(i2);
            }
        }
    }
    __syncthreads();

    if (tid < BM) {
        const float* p = &tl[tid * TROW];
        float s1 = p[0], s2 = p[2];
        int i1 = __float_as_int(p[1]), i2 = __float_as_int(p[3]);
        #pragma unroll
        for (int e = 1; e < 8; ++e) {
            const float* q = p + e * 4;
            merge2(s1, i1, s2, i2, q[0], __float_as_int(q[1]),
                   q[2], __float_as_int(q[3]));
        }
        const int token = mbase + tid;
        slab[(size_t)token * NSLAB + nb] =
            (float4){s1, __int_as_float(i1), s2, __int_as_float(i2)};
    }
}

__global__ __launch_bounds__(256) void vq_pick(
    const float* __restrict__ z, const float* __restrict__ emb,
    const float4* __restrict__ slab, float* __restrict__ out) {
    const int token = blockIdx.x * 4 + (threadIdx.x >> 6);
    const int lane = threadIdx.x & 63;

    const float4 c = slab[(size_t)token * NSLAB + lane];
    const float cs1 = c.x, cs2 = c.z;
    const int ci1 = __float_as_int(c.y), ci2 = __float_as_int(c.w);

    float bs = cs1;
    int bi = ci1;
    #pragma unroll
    for (int off = 32; off; off >>= 1) {
        const float os = __shfl_xor(bs, off);
        const int oi = __shfl_xor(bi, off);
        if (lexlt(os, oi, bs, bi)) { bs = os; bi = oi; }
    }

    const float tau = 0.25f;   // >> 2*max bf16-rounding score error (~0.07)
    const unsigned long long m1 = __ballot(cs1 <= bs + tau);
    const unsigned long long m2 = __ballot(cs2 <= bs + tau);
    int winner = bi;

    if (__popcll(m1) + __popcll(m2) > 1) {
        const float4 z4 = *reinterpret_cast<const float4*>(
            z + (size_t)token * C + lane * 4);
        float best = 3.4e38f;
        int besti = 0x7fffffff;
        #pragma unroll 1
        for (int pass = 0; pass < 2; ++pass) {
            unsigned long long mm = pass ? m2 : m1;
            while (mm) {
                const int l = __builtin_ctzll(mm);
                mm &= mm - 1;
                const int cidx = __shfl(pass ? ci2 : ci1, l);
                const float4 e4 = *reinterpret_cast<const float4*>(
                    emb + (size_t)cidx * C + lane * 4);
                float p = 0.5f * (e4.x * e4.x + e4.y * e4.y + e4.z * e4.z +
                                  e4.w * e4.w)
                        - (z4.x * e4.x + z4.y * e4.y + z4.z * e4.z + z4.w * e4.w);
                #pragma unroll
                for (int off = 32; off; off >>= 1) p += __shfl_xor(p, off);
                if (lexlt(p, cidx, best, besti)) { best = p; besti = cidx; }
            }
        }
        winner = besti;
    }

    const float4 v = *reinterpret_cast<const float4*>(
        emb + (size_t)winner * C + lane * 4);
    *reinterpret_cast<float4*>(out + (size_t)token * C + lane * 4) = v;
}

extern "C" void kernel_launch(void* const* d_in, const int* in_sizes, int n_in,
                              void* d_out, int out_size, void* d_ws, size_t ws_size,
                              hipStream_t stream) {
    const float* z = (const float*)d_in[0];
    const float* emb = (const float*)d_in[1];
    float* out = (float*)d_out;

    char* w = (char*)d_ws;
    float* hn = (float*)w;            w += (size_t)NCODE * 4;
    ushort* zb = (ushort*)w;          w += (size_t)MTOK * C * 2;
    ushort* eb = (ushort*)w;          w += (size_t)NCODE * C * 2;
    float4* slab = (float4*)w;        // MTOK*NSLAB*16B = 16.8 MB

    vq_norms<<<NCODE, 64, 0, stream>>>(emb, hn);
    vq_cast<<<1024, 256, 0, stream>>>(z, zb, MTOK * C / 4);
    vq_cast<<<512, 256, 0, stream>>>(emb, eb, NCODE * C / 4);

    vq_gemm<<<dim3(MTOK / BM, NCODE / BN), TPB, 0, stream>>>(zb, eb, hn, slab);

    vq_pick<<<MTOK / 4, 256, 0, stream>>>(z, emb, slab, out);
}